// Round 10
// baseline (530.089 us; speedup 1.0000x reference)
//
#include <hip/hip_runtime.h>
#include <hip/hip_fp16.h>

#define N_NODES 30000
#define N_EDGES 480000
#define NB 64           // blocks per etype for counting sort
#define CHUNK 7500      // N_EDGES / NB  (< 65536 so u16 ranks/counts are safe)

typedef _Float16 f16;
typedef f16 f16x8 __attribute__((ext_vector_type(8)));
typedef float f32x4 __attribute__((ext_vector_type(4)));

// ================= one-time converts =================
__global__ void convert_h_kernel(const float* __restrict__ in, f16* __restrict__ out, int n8)
{
  int i = blockIdx.x * 256 + threadIdx.x;
  if (i >= n8) return;
  float4 a = *(const float4*)(in + (size_t)i * 8);
  float4 b = *(const float4*)(in + (size_t)i * 8 + 4);
  f16x8 v;
  v[0] = (f16)a.x; v[1] = (f16)a.y; v[2] = (f16)a.z; v[3] = (f16)a.w;
  v[4] = (f16)b.x; v[5] = (f16)b.y; v[6] = (f16)b.z; v[7] = (f16)b.w;
  *(f16x8*)(out + (size_t)i * 8) = v;
}

// out[m][n][k] = (f16) in_m[k][n], 4 matrices 256x256, blockIdx.y = m
__global__ void transpose_w_kernel(const float* __restrict__ s0, const float* __restrict__ s1,
                                   const float* __restrict__ s2, const float* __restrict__ s3,
                                   f16* __restrict__ out)
{
  int m = blockIdx.y;
  const float* in = (m == 0) ? s0 : (m == 1) ? s1 : (m == 2) ? s2 : s3;
  int t = blockIdx.x * 256 + threadIdx.x;   // 65536
  int n = t >> 8, k = t & 255;
  out[(size_t)m * 65536 + t] = (f16)in[k * 256 + n];
}

// ================= MFMA GEMM: 128x64 tile, B-in-LDS-once, A direct from global =================
template<int MODE>
__global__ __launch_bounds__(256)
void gemm_mfma(const f16* __restrict__ A, const f16* __restrict__ BT,
               f16* __restrict__ Ch, float* __restrict__ Cf, int M,
               const float* __restrict__ al, const float* __restrict__ ar,
               float* __restrict__ el, float* __restrict__ er,
               const float* __restrict__ tvec, const float* __restrict__ bvec,
               const float* __restrict__ Wp1, const float* __restrict__ Wp2,
               const float* __restrict__ bp, int ldc, int coff)
{
  __shared__ alignas(16) f16 Bs[64][264];   // +8 f16 pad
  __shared__ float W1s[8][64];
  __shared__ float W2s[8][64];
  __shared__ float t_lds[128][8];
  __shared__ float b_lds[128][8];

  const int tid = threadIdx.x;
  const int lane = tid & 63, wv = tid >> 6;
  const int l15 = lane & 15, lq = lane >> 4;
  const int bm = blockIdx.x * 128;
  const int ct = blockIdx.y;
  const int bn = ct * 64;

#pragma unroll
  for (int i = 0; i < 8; ++i) {
    int seg = tid + i * 256;
    int row = seg >> 5;
    int cs = (seg & 31) * 8;
    *(uint4*)&Bs[row][cs] = *(const uint4*)&BT[(size_t)(bn + row) * 256 + cs];
  }

  if (MODE == 1) {
    if (tid < 128) {
      int r = tid >> 4, c4 = (tid & 15) * 4;
      *(float4*)&W1s[r][c4] = *(const float4*)&Wp1[r * 256 + bn + c4];
    } else {
      int t2 = tid - 128;
      int r = t2 >> 4, c4 = (t2 & 15) * 4;
      *(float4*)&W2s[r][c4] = *(const float4*)&Wp2[r * 256 + bn + c4];
    }
    {
      int r = tid >> 1, c = (tid & 1) * 4;
      int row = bm + r;
      float4 tv = make_float4(0.f, 0.f, 0.f, 0.f), bv2 = tv;
      if (row < M) {
        tv  = *(const float4*)&tvec[(size_t)row * 8 + c];
        bv2 = *(const float4*)&bvec[(size_t)row * 8 + c];
      }
      *(float4*)&t_lds[r][c] = tv;
      *(float4*)&b_lds[r][c] = bv2;
    }
  }
  __syncthreads();

  const int r0 = bm + wv * 32 + l15;
  const int r1 = r0 + 16;
  const bool ok0 = r0 < M, ok1 = r1 < M;
  const f16* Arow0 = A + (size_t)r0 * 256;
  const f16* Arow1 = A + (size_t)r1 * 256;

  f32x4 acc[2][4] = {};

#pragma unroll
  for (int k0 = 0; k0 < 256; k0 += 32) {
    int ko = k0 + lq * 8;
    f16x8 a0 = {0, 0, 0, 0, 0, 0, 0, 0};
    f16x8 a1 = {0, 0, 0, 0, 0, 0, 0, 0};
    if (ok0) a0 = *(const f16x8*)(Arow0 + ko);
    if (ok1) a1 = *(const f16x8*)(Arow1 + ko);
#pragma unroll
    for (int nf = 0; nf < 4; ++nf) {
      f16x8 bf = *(const f16x8*)&Bs[nf * 16 + l15][ko];
      acc[0][nf] = __builtin_amdgcn_mfma_f32_16x16x32_f16(a0, bf, acc[0][nf], 0, 0, 0);
      acc[1][nf] = __builtin_amdgcn_mfma_f32_16x16x32_f16(a1, bf, acc[1][nf], 0, 0, 0);
    }
  }

  if (MODE == 0) {
    float alv[4], arv[4];
#pragma unroll
    for (int nf = 0; nf < 4; ++nf) {
      alv[nf] = al[bn + nf * 16 + l15];
      arv[nf] = ar[bn + nf * 16 + l15];
    }
#pragma unroll
    for (int m = 0; m < 2; ++m)
#pragma unroll
      for (int i = 0; i < 4; ++i) {
        int row = bm + wv * 32 + m * 16 + lq * 4 + i;
        float pe = 0.f, pr = 0.f;
#pragma unroll
        for (int nf = 0; nf < 4; ++nf) {
          pe = fmaf(acc[m][nf][i], alv[nf], pe);
          pr = fmaf(acc[m][nf][i], arv[nf], pr);
        }
#pragma unroll
        for (int o = 8; o >= 1; o >>= 1) {
          pe += __shfl_xor(pe, o, 64);
          pr += __shfl_xor(pr, o, 64);
        }
        if (row < M) {
          if (l15 == 0) {
            el[row * 4 + ct] = pe;
            er[row * 4 + ct] = pr;
          }
#pragma unroll
          for (int nf = 0; nf < 4; ++nf)
            Ch[(size_t)row * 256 + bn + nf * 16 + l15] = (f16)acc[m][nf][i];
        }
      }
  } else {
    float bpv[4];
#pragma unroll
    for (int nf = 0; nf < 4; ++nf) bpv[nf] = bp[bn + nf * 16 + l15];
#pragma unroll
    for (int m = 0; m < 2; ++m)
#pragma unroll
      for (int i = 0; i < 4; ++i) {
        int rl = wv * 32 + m * 16 + lq * 4 + i;
        int row = bm + rl;
        if (row >= M) continue;
#pragma unroll
        for (int nf = 0; nf < 4; ++nf) {
          int c = nf * 16 + l15;
          float v = acc[m][nf][i] + bpv[nf];
#pragma unroll
          for (int k = 0; k < 8; ++k) {
            v = fmaf(t_lds[rl][k], W1s[k][c], v);
            v = fmaf(b_lds[rl][k], W2s[k][c], v);
          }
          Cf[(size_t)row * ldc + coff + bn + c] = v;
        }
      }
  }
}

// ============== CSR build pass 1: LDS histogram + per-edge local rank ==============
__global__ __launch_bounds__(512)
void hist_kernel(const int* __restrict__ d0, const int* __restrict__ d1,
                 const int* __restrict__ d2, unsigned short* __restrict__ ghist,
                 unsigned short* __restrict__ rank16)
{
  __shared__ unsigned int h32[N_NODES / 2];
  int et = blockIdx.y, b = blockIdx.x, tid = threadIdx.x;
  const int* dst = (et == 0) ? d0 : (et == 1) ? d1 : d2;
  for (int i = tid; i < N_NODES / 2; i += 512) h32[i] = 0u;
  __syncthreads();
  int e0 = b * CHUNK;
  for (int i = tid; i < CHUNK; i += 512) {
    int e = e0 + i;
    int d = dst[e];
    unsigned int sh = (d & 1) * 16;
    unsigned int old = atomicAdd(&h32[d >> 1], 1u << sh);
    rank16[(size_t)et * N_EDGES + e] = (unsigned short)((old >> sh) & 0xFFFFu);
  }
  __syncthreads();
  unsigned short* gh = ghist + ((size_t)(et * NB + b)) * N_NODES;
  for (int d = tid; d < N_NODES; d += 512)
    gh[d] = (unsigned short)((h32[d >> 1] >> ((d & 1) * 16)) & 0xFFFFu);
}

// ============== pass 2: per-dst exclusive prefix over NB blocks + totals ==============
__global__ __launch_bounds__(256)
void blockpfx_kernel(unsigned short* __restrict__ ghist, int* __restrict__ counts)
{
  int d = blockIdx.x * 256 + threadIdx.x;
  int et = blockIdx.y;
  if (d >= N_NODES) return;
  int running = 0;
#pragma unroll
  for (int b = 0; b < NB; ++b) {
    size_t idx = ((size_t)(et * NB + b)) * N_NODES + d;
    int v = ghist[idx];
    ghist[idx] = (unsigned short)running;
    running += v;
  }
  counts[et * N_NODES + d] = running;
}

// ============== batched scan (blockIdx.x = etype) ==============
__global__ __launch_bounds__(1024)
void scan_kernel(int* __restrict__ cc_all, int* __restrict__ off_all, int n, int total)
{
  int et = blockIdx.x;
  int* cc = cc_all + (size_t)et * n;
  int* off = off_all + (size_t)et * (n + 1);
  __shared__ int wsum[16];
  __shared__ int woff[16];
  __shared__ int s_carry, s_chunk;
  int tid = threadIdx.x;
  int lane = tid & 63, wid = tid >> 6;
  if (tid == 0) s_carry = 0;
  __syncthreads();
  for (int base = 0; base < n; base += 1024) {
    int i = base + tid;
    int v = (i < n) ? cc[i] : 0;
    int x = v;
#pragma unroll
    for (int s = 1; s < 64; s <<= 1) {
      int y = __shfl_up(x, s, 64);
      if (lane >= s) x += y;
    }
    if (lane == 63) wsum[wid] = x;
    __syncthreads();
    if (wid == 0 && lane < 16) {
      int ws_ = wsum[lane];
      int xx = ws_;
#pragma unroll
      for (int s = 1; s < 16; s <<= 1) {
        int y = __shfl_up(xx, s, 64);
        if (lane >= s) xx += y;
      }
      woff[lane] = xx - ws_;
      if (lane == 15) s_chunk = xx;
    }
    __syncthreads();
    int excl = s_carry + woff[wid] + (x - v);
    if (i < n) { off[i] = excl; cc[i] = excl; }
    __syncthreads();
    if (tid == 0) s_carry += s_chunk;
    __syncthreads();
  }
  if (tid == 0) off[n] = total;
}

// ============== pass 4: place packed payload {src|dst<<16, ew} (single 8B scatter) ==============
__global__ __launch_bounds__(256)
void place_kernel(const int* __restrict__ d0, const int* __restrict__ d1,
                  const int* __restrict__ d2,
                  const int* __restrict__ s0, const int* __restrict__ s1,
                  const int* __restrict__ s2,
                  const float* __restrict__ w0, const float* __restrict__ w1,
                  const float* __restrict__ w2,
                  const int* __restrict__ off, const unsigned short* __restrict__ ghist,
                  const unsigned short* __restrict__ rank16,
                  int2* __restrict__ csr_pay)
{
  int e = blockIdx.x * 256 + threadIdx.x;
  if (e >= N_EDGES) return;
  int et = blockIdx.y;
  const int* dst = (et == 0) ? d0 : (et == 1) ? d1 : d2;
  const int* src = (et == 0) ? s0 : (et == 1) ? s1 : s2;
  const float* ew = (et == 0) ? w0 : (et == 1) ? w1 : w2;
  int d = dst[e];
  int b = e / CHUNK;
  int pos = off[et * (N_NODES + 1) + d]
          + (int)ghist[((size_t)(et * NB + b)) * N_NODES + d]
          + (int)rank16[(size_t)et * N_EDGES + e];
  csr_pay[(size_t)et * N_EDGES + pos] = make_int2(src[e] | (d << 16), __float_as_int(ew[e]));
}

// ============== per-etype edge-parallel coefficients: {src, ex01(f16), ex23(f16), ew} ==============
__global__ __launch_bounds__(256)
void coef_kernel(const int2* __restrict__ csr_pay, const float* __restrict__ el,
                 const float* __restrict__ er, int4* __restrict__ csr_cf)
{
  int e = blockIdx.x * 256 + threadIdx.x;
  if (e >= N_EDGES) return;
  int2 pay = csr_pay[e];
  int s = pay.x & 0xFFFF;
  int d = pay.x >> 16;             // dst < 30000, sign bit clear
  float4 l4 = *(const float4*)&el[(size_t)s * 4];
  float4 r4 = *(const float4*)&er[(size_t)d * 4];
  float v0 = l4.x + r4.x; v0 = v0 > 0.f ? v0 : 0.2f * v0;
  float v1 = l4.y + r4.y; v1 = v1 > 0.f ? v1 : 0.2f * v1;
  float v2 = l4.z + r4.z; v2 = v2 > 0.f ? v2 : 0.2f * v2;
  float v3 = l4.w + r4.w; v3 = v3 > 0.f ? v3 : 0.2f * v3;
  __half2 e01 = __floats2half2_rn(__expf(v0), __expf(v1));
  __half2 e23 = __floats2half2_rn(__expf(v2), __expf(v3));
  csr_cf[e] = make_int4(s, *(int*)&e01, *(int*)&e23, pay.y);
}

// ============== wave-per-node aggregation: 16-deep unrolled gathers + fused gt/gb projection ==============
__global__ __launch_bounds__(256)
void aggregate_kernel(const int* __restrict__ off, const int4* __restrict__ csr_cf,
                      const __half* __restrict__ feat, const float* __restrict__ bias,
                      const float* __restrict__ Wt, const float* __restrict__ Wb,
                      __half* __restrict__ gat, float* __restrict__ gt, float* __restrict__ gb,
                      int n_nodes)
{
  int tid = threadIdx.x;
  int lane = tid & 63, wv = tid >> 6;
  int n = blockIdx.x * 4 + wv;
  if (n >= n_nodes) return;
  int hd = lane >> 4;

  __shared__ int   s_src[4][16];
  __shared__ float s_cf[4][16][4];       // ex * ew
  __shared__ float s_ex[4][16][4];       // ex (for denom)

  int e0 = off[n], e1 = off[n + 1];
  float4 bv = *(const float4*)&bias[lane * 4];
  float ac0 = 0.f, ac1 = 0.f, ac2 = 0.f, ac3 = 0.f, dn = 0.f;

  for (int base = e0; base < e1; base += 16) {
    int cnt = min(16, e1 - base);
    if (lane < cnt) {
      int4 c4 = csr_cf[base + lane];
      float w = __int_as_float(c4.w);
      float2 e01 = __half22float2(*(__half2*)&c4.y);
      float2 e23 = __half22float2(*(__half2*)&c4.z);
      s_src[wv][lane] = c4.x;
      s_ex[wv][lane][0] = e01.x; s_ex[wv][lane][1] = e01.y;
      s_ex[wv][lane][2] = e23.x; s_ex[wv][lane][3] = e23.y;
      s_cf[wv][lane][0] = e01.x * w; s_cf[wv][lane][1] = e01.y * w;
      s_cf[wv][lane][2] = e23.x * w; s_cf[wv][lane][3] = e23.y * w;
    }
    __builtin_amdgcn_wave_barrier();

    // gather coefficients & rows (clamped: k>=cnt contributes 0 via zero coef)
    float kcf[16];
    const __half* rowp[16];
#pragma unroll
    for (int k = 0; k < 16; ++k) {
      bool on = k < cnt;
      int kk = on ? k : 0;
      rowp[k] = feat + (size_t)s_src[wv][kk] * 256 + lane * 4;
      kcf[k] = on ? s_cf[wv][kk][hd] : 0.f;
      dn += on ? s_ex[wv][kk][hd] : 0.f;
    }
    // issue all 16 row gathers back-to-back
    uint2 u[16];
#pragma unroll
    for (int k = 0; k < 16; ++k) u[k] = *(const uint2*)rowp[k];
#pragma unroll
    for (int k = 0; k < 16; ++k) {
      float2 f01 = __half22float2(*(__half2*)&u[k].x);
      float2 f23 = __half22float2(*(__half2*)&u[k].y);
      ac0 = fmaf(kcf[k], f01.x, ac0); ac1 = fmaf(kcf[k], f01.y, ac1);
      ac2 = fmaf(kcf[k], f23.x, ac2); ac3 = fmaf(kcf[k], f23.y, ac3);
    }
    __builtin_amdgcn_wave_barrier();
  }

  float invd = (dn != 0.f) ? 1.f / dn : 0.f;
  float v0 = ac0 * invd + bv.x;
  float v1 = ac1 * invd + bv.y;
  float v2 = ac2 * invd + bv.z;
  float v3 = ac3 * invd + bv.w;

  __half2 h01 = __floats2half2_rn(v0, v1);
  __half2 h23 = __floats2half2_rn(v2, v3);
  uint2 st;
  st.x = *(unsigned int*)&h01;
  st.y = *(unsigned int*)&h23;
  *(uint2*)&gat[(size_t)n * 256 + lane * 4] = st;

  // fused projection: p[0..7] = gt partials, p[8..15] = gb partials (in-wave)
  float p[16];
#pragma unroll
  for (int j = 0; j < 16; ++j) p[j] = 0.f;
  float fv[4] = {v0, v1, v2, v3};
#pragma unroll
  for (int r = 0; r < 4; ++r) {
    int c = lane * 4 + r;
    const float* wtr = &Wt[(size_t)c * 8];
    const float* wbr = &Wb[(size_t)c * 8];
#pragma unroll
    for (int j = 0; j < 8; ++j) {
      p[j]     = fmaf(fv[r], wtr[j], p[j]);
      p[8 + j] = fmaf(fv[r], wbr[j], p[8 + j]);
    }
  }
#pragma unroll
  for (int o = 32; o >= 1; o >>= 1) {
#pragma unroll
    for (int j = 0; j < 16; ++j) p[j] += __shfl_xor(p[j], o, 64);
  }
  if (lane == 0) {
#pragma unroll
    for (int j = 0; j < 8; ++j) {
      gt[(size_t)n * 8 + j] = p[j];
      gb[(size_t)n * 8 + j] = p[8 + j];
    }
  }
}

// ============== enhance: wave-per-node; rank + tiny gt/gb gathers ==============
__global__ __launch_bounds__(256)
void enhance_pool_kernel(const int* __restrict__ nbr_idx, const float* __restrict__ nbr_w,
                         const float* __restrict__ gt, const float* __restrict__ gb,
                         const float* __restrict__ bt, const float* __restrict__ bb,
                         float* __restrict__ tvec, float* __restrict__ bvec, int n_nodes)
{
  int n = (blockIdx.x * 256 + threadIdx.x) >> 6;
  int lane = threadIdx.x & 63;
  if (n >= n_nodes) return;
  const int l16 = lane & 15;

  float w = nbr_w[(size_t)n * 16 + l16];
  int idx = nbr_idx[(size_t)n * 16 + l16];

  int rhi = 0, rlo = 0;
#pragma unroll
  for (int i = 0; i < 16; ++i) {
    float wi = __shfl(w, i, 64);
    rhi += (wi > w) || (wi == w && i < l16);
    rlo += (wi < w) || (wi == w && i < l16);
  }

  int rows[7];
#pragma unroll
  for (int q = 0; q < 5; ++q) {
    unsigned long long m = __ballot(lane < 16 && rhi == q);
    rows[q] = __shfl(idx, __ffsll(m) - 1, 64);
  }
#pragma unroll
  for (int q = 0; q < 2; ++q) {
    unsigned long long m = __ballot(lane < 16 && rlo == q);
    rows[5 + q] = __shfl(idx, __ffsll(m) - 1, 64);
  }

  int j = lane & 7;
  if (lane < 8) {
    float s = 0.f;
#pragma unroll
    for (int q = 0; q < 5; ++q) s += gt[(size_t)rows[q] * 8 + j];
    tvec[(size_t)n * 8 + j] = s * 0.2f + bt[j];
  } else if (lane < 16) {
    float s = gb[(size_t)rows[5] * 8 + j] + gb[(size_t)rows[6] * 8 + j];
    bvec[(size_t)n * 8 + j] = s * 0.5f + bb[j];
  }
}

extern "C" void kernel_launch(void* const* d_in, const int* in_sizes, int n_in,
                              void* d_out, int out_size, void* d_ws, size_t ws_size,
                              hipStream_t stream)
{
  const int N_ = N_NODES;
  const int E_ = N_EDGES;

  const float* h = (const float*)d_in[0];
  const float* Wt = (const float*)d_in[28];
  const float* bt = (const float*)d_in[29];
  const float* Wb = (const float*)d_in[30];
  const float* bb = (const float*)d_in[31];
  const float* Wp = (const float*)d_in[32];
  const float* bp = (const float*)d_in[33];
  float* out = (float*)d_out;

  char* wsb = (char*)d_ws;
  size_t o = 0;
  auto alloc = [&](size_t bytes) -> void* {
    void* p = wsb + o;
    o = (o + bytes + 255) & ~(size_t)255;
    return p;
  };
  f16*  hf    = (f16*)alloc((size_t)N_ * 256 * 2);
  f16*  feat  = (f16*)alloc((size_t)N_ * 256 * 2);
  f16*  gat   = (f16*)alloc((size_t)N_ * 256 * 2);
  f16*  WT    = (f16*)alloc((size_t)4 * 256 * 256 * 2);   // 3x W + WpT
  float* el     = (float*)alloc((size_t)N_ * 4 * 4);
  float* er     = (float*)alloc((size_t)N_ * 4 * 4);
  float* gt     = (float*)alloc((size_t)N_ * 8 * 4);
  float* gb     = (float*)alloc((size_t)N_ * 8 * 4);
  float* tvec   = (float*)alloc((size_t)N_ * 8 * 4);
  float* bvec   = (float*)alloc((size_t)N_ * 8 * 4);
  int*   off    = (int*)alloc((size_t)3 * (N_ + 1) * 4);
  int*   counts = (int*)alloc((size_t)3 * N_ * 4);
  unsigned short* ghist = (unsigned short*)alloc((size_t)3 * NB * N_ * 2);  // 11.5 MB
  unsigned short* rank16 = (unsigned short*)alloc((size_t)3 * E_ * 2);
  int2*  csr_pay = (int2*)alloc((size_t)3 * E_ * 8);
  // csr_cf aliases ghist (dead after place_kernel): E*16 = 7.68 MB <= 11.5 MB
  int4*  csr_cf = (int4*)ghist;
  (void)ws_size; (void)in_sizes; (void)n_in; (void)out_size;

  const int row_blocks = (N_ + 127) / 128;  // 235
  const int edge_blocks = (E_ + 255) / 256; // 1875
  const int wave_blocks = (N_ + 3) / 4;     // 7500

  const int* d_dst0 = (const int*)d_in[1 + 0 * 9 + 1];
  const int* d_dst1 = (const int*)d_in[1 + 1 * 9 + 1];
  const int* d_dst2 = (const int*)d_in[1 + 2 * 9 + 1];
  const int* d_src0 = (const int*)d_in[1 + 0 * 9 + 0];
  const int* d_src1 = (const int*)d_in[1 + 1 * 9 + 0];
  const int* d_src2 = (const int*)d_in[1 + 2 * 9 + 0];
  const float* d_ew0 = (const float*)d_in[1 + 0 * 9 + 2];
  const float* d_ew1 = (const float*)d_in[1 + 1 * 9 + 2];
  const float* d_ew2 = (const float*)d_in[1 + 2 * 9 + 2];

  // one-time conversions (independent of CSR build)
  convert_h_kernel<<<(N_ * 256 / 8 + 255) / 256, 256, 0, stream>>>(h, hf, N_ * 256 / 8);
  transpose_w_kernel<<<dim3(256, 4), 256, 0, stream>>>(
      (const float*)d_in[1 + 0 * 9 + 5], (const float*)d_in[1 + 1 * 9 + 5],
      (const float*)d_in[1 + 2 * 9 + 5], Wp, WT);
  f16* WpT = WT + (size_t)3 * 65536;

  // atomic-free CSR build (batched over etypes)
  hist_kernel<<<dim3(NB, 3), 512, 0, stream>>>(d_dst0, d_dst1, d_dst2, ghist, rank16);
  blockpfx_kernel<<<dim3((N_ + 255) / 256, 3), 256, 0, stream>>>(ghist, counts);
  scan_kernel<<<3, 1024, 0, stream>>>(counts, off, N_, E_);
  place_kernel<<<dim3(edge_blocks, 3), 256, 0, stream>>>(
      d_dst0, d_dst1, d_dst2, d_src0, d_src1, d_src2, d_ew0, d_ew1, d_ew2,
      off, ghist, rank16, csr_pay);

  for (int et = 0; et < 3; ++et) {
    const int base = 1 + et * 9;
    const int* nbr_idx = (const int*)d_in[base + 3];
    const float* nbr_w = (const float*)d_in[base + 4];
    const float* al = (const float*)d_in[base + 6];
    const float* ar = (const float*)d_in[base + 7];
    const float* b = (const float*)d_in[base + 8];

    gemm_mfma<0><<<dim3(row_blocks, 4), 256, 0, stream>>>(
        hf, WT + (size_t)et * 65536, feat, nullptr, N_, al, ar, el, er,
        nullptr, nullptr, nullptr, nullptr, nullptr, 256, 0);

    coef_kernel<<<edge_blocks, 256, 0, stream>>>(
        csr_pay + (size_t)et * E_, el, er, csr_cf);

    aggregate_kernel<<<wave_blocks, 256, 0, stream>>>(
        off + (size_t)et * (N_ + 1), csr_cf, (const __half*)feat, b, Wt, Wb,
        (__half*)gat, gt, gb, N_);

    enhance_pool_kernel<<<wave_blocks, 256, 0, stream>>>(
        nbr_idx, nbr_w, gt, gb, bt, bb, tvec, bvec, N_);

    gemm_mfma<1><<<dim3(row_blocks, 4), 256, 0, stream>>>(
        gat, WpT, nullptr, out, N_, nullptr, nullptr, nullptr, nullptr,
        tvec, bvec, Wp + 256 * 256, Wp + 264 * 256, bp, 768, et * 256);
  }
}

// Round 11
// 508.640 us; speedup vs baseline: 1.0422x; 1.0422x over previous
//
#include <hip/hip_runtime.h>
#include <hip/hip_fp16.h>

#define N_NODES 30000
#define N_EDGES 480000
#define NB 64           // blocks per etype for counting sort
#define CHUNK 7500      // N_EDGES / NB  (< 65536 so u16 ranks/counts are safe)

typedef _Float16 f16;
typedef f16 f16x8 __attribute__((ext_vector_type(8)));
typedef float f32x4 __attribute__((ext_vector_type(4)));

// ================= one-time converts =================
__global__ void convert_h_kernel(const float* __restrict__ in, f16* __restrict__ out, int n8)
{
  int i = blockIdx.x * 256 + threadIdx.x;
  if (i >= n8) return;
  float4 a = *(const float4*)(in + (size_t)i * 8);
  float4 b = *(const float4*)(in + (size_t)i * 8 + 4);
  f16x8 v;
  v[0] = (f16)a.x; v[1] = (f16)a.y; v[2] = (f16)a.z; v[3] = (f16)a.w;
  v[4] = (f16)b.x; v[5] = (f16)b.y; v[6] = (f16)b.z; v[7] = (f16)b.w;
  *(f16x8*)(out + (size_t)i * 8) = v;
}

// out[m][n][k] = (f16) in_m[k][n], 4 matrices 256x256, blockIdx.y = m
__global__ void transpose_w_kernel(const float* __restrict__ s0, const float* __restrict__ s1,
                                   const float* __restrict__ s2, const float* __restrict__ s3,
                                   f16* __restrict__ out)
{
  int m = blockIdx.y;
  const float* in = (m == 0) ? s0 : (m == 1) ? s1 : (m == 2) ? s2 : s3;
  int t = blockIdx.x * 256 + threadIdx.x;   // 65536
  int n = t >> 8, k = t & 255;
  out[(size_t)m * 65536 + t] = (f16)in[k * 256 + n];
}

// ================= MFMA GEMM: 128x64 tile, B-in-LDS-once, A direct from global =================
template<int MODE>
__global__ __launch_bounds__(256)
void gemm_mfma(const f16* __restrict__ A, const f16* __restrict__ BT,
               f16* __restrict__ Ch, float* __restrict__ Cf, int M,
               const float* __restrict__ al, const float* __restrict__ ar,
               float* __restrict__ el, float* __restrict__ er,
               const float* __restrict__ tvec, const float* __restrict__ bvec,
               const float* __restrict__ Wp1, const float* __restrict__ Wp2,
               const float* __restrict__ bp, int ldc, int coff)
{
  __shared__ alignas(16) f16 Bs[64][264];   // +8 f16 pad
  __shared__ float W1s[8][64];
  __shared__ float W2s[8][64];
  __shared__ float t_lds[128][8];
  __shared__ float b_lds[128][8];

  const int tid = threadIdx.x;
  const int lane = tid & 63, wv = tid >> 6;
  const int l15 = lane & 15, lq = lane >> 4;
  const int bm = blockIdx.x * 128;
  const int ct = blockIdx.y;
  const int bn = ct * 64;

#pragma unroll
  for (int i = 0; i < 8; ++i) {
    int seg = tid + i * 256;
    int row = seg >> 5;
    int cs = (seg & 31) * 8;
    *(uint4*)&Bs[row][cs] = *(const uint4*)&BT[(size_t)(bn + row) * 256 + cs];
  }

  if (MODE == 1) {
    if (tid < 128) {
      int r = tid >> 4, c4 = (tid & 15) * 4;
      *(float4*)&W1s[r][c4] = *(const float4*)&Wp1[r * 256 + bn + c4];
    } else {
      int t2 = tid - 128;
      int r = t2 >> 4, c4 = (t2 & 15) * 4;
      *(float4*)&W2s[r][c4] = *(const float4*)&Wp2[r * 256 + bn + c4];
    }
    {
      int r = tid >> 1, c = (tid & 1) * 4;
      int row = bm + r;
      float4 tv = make_float4(0.f, 0.f, 0.f, 0.f), bv2 = tv;
      if (row < M) {
        tv  = *(const float4*)&tvec[(size_t)row * 8 + c];
        bv2 = *(const float4*)&bvec[(size_t)row * 8 + c];
      }
      *(float4*)&t_lds[r][c] = tv;
      *(float4*)&b_lds[r][c] = bv2;
    }
  }
  __syncthreads();

  const int r0 = bm + wv * 32 + l15;
  const int r1 = r0 + 16;
  const bool ok0 = r0 < M, ok1 = r1 < M;
  const f16* Arow0 = A + (size_t)r0 * 256;
  const f16* Arow1 = A + (size_t)r1 * 256;

  f32x4 acc[2][4] = {};

#pragma unroll
  for (int k0 = 0; k0 < 256; k0 += 32) {
    int ko = k0 + lq * 8;
    f16x8 a0 = {0, 0, 0, 0, 0, 0, 0, 0};
    f16x8 a1 = {0, 0, 0, 0, 0, 0, 0, 0};
    if (ok0) a0 = *(const f16x8*)(Arow0 + ko);
    if (ok1) a1 = *(const f16x8*)(Arow1 + ko);
#pragma unroll
    for (int nf = 0; nf < 4; ++nf) {
      f16x8 bf = *(const f16x8*)&Bs[nf * 16 + l15][ko];
      acc[0][nf] = __builtin_amdgcn_mfma_f32_16x16x32_f16(a0, bf, acc[0][nf], 0, 0, 0);
      acc[1][nf] = __builtin_amdgcn_mfma_f32_16x16x32_f16(a1, bf, acc[1][nf], 0, 0, 0);
    }
  }

  if (MODE == 0) {
    float alv[4], arv[4];
#pragma unroll
    for (int nf = 0; nf < 4; ++nf) {
      alv[nf] = al[bn + nf * 16 + l15];
      arv[nf] = ar[bn + nf * 16 + l15];
    }
#pragma unroll
    for (int m = 0; m < 2; ++m)
#pragma unroll
      for (int i = 0; i < 4; ++i) {
        int row = bm + wv * 32 + m * 16 + lq * 4 + i;
        float pe = 0.f, pr = 0.f;
#pragma unroll
        for (int nf = 0; nf < 4; ++nf) {
          pe = fmaf(acc[m][nf][i], alv[nf], pe);
          pr = fmaf(acc[m][nf][i], arv[nf], pr);
        }
#pragma unroll
        for (int o = 8; o >= 1; o >>= 1) {
          pe += __shfl_xor(pe, o, 64);
          pr += __shfl_xor(pr, o, 64);
        }
        if (row < M) {
          if (l15 == 0) {
            el[row * 4 + ct] = pe;
            er[row * 4 + ct] = pr;
          }
#pragma unroll
          for (int nf = 0; nf < 4; ++nf)
            Ch[(size_t)row * 256 + bn + nf * 16 + l15] = (f16)acc[m][nf][i];
        }
      }
  } else {
    float bpv[4];
#pragma unroll
    for (int nf = 0; nf < 4; ++nf) bpv[nf] = bp[bn + nf * 16 + l15];
#pragma unroll
    for (int m = 0; m < 2; ++m)
#pragma unroll
      for (int i = 0; i < 4; ++i) {
        int rl = wv * 32 + m * 16 + lq * 4 + i;
        int row = bm + rl;
        if (row >= M) continue;
#pragma unroll
        for (int nf = 0; nf < 4; ++nf) {
          int c = nf * 16 + l15;
          float v = acc[m][nf][i] + bpv[nf];
#pragma unroll
          for (int k = 0; k < 8; ++k) {
            v = fmaf(t_lds[rl][k], W1s[k][c], v);
            v = fmaf(b_lds[rl][k], W2s[k][c], v);
          }
          Cf[(size_t)row * ldc + coff + bn + c] = v;
        }
      }
  }
}

// ============== CSR build pass 1: LDS histogram + per-edge local rank ==============
__global__ __launch_bounds__(512)
void hist_kernel(const int* __restrict__ d0, const int* __restrict__ d1,
                 const int* __restrict__ d2, unsigned short* __restrict__ ghist,
                 unsigned short* __restrict__ rank16)
{
  __shared__ unsigned int h32[N_NODES / 2];
  int et = blockIdx.y, b = blockIdx.x, tid = threadIdx.x;
  const int* dst = (et == 0) ? d0 : (et == 1) ? d1 : d2;
  for (int i = tid; i < N_NODES / 2; i += 512) h32[i] = 0u;
  __syncthreads();
  int e0 = b * CHUNK;
  for (int i = tid; i < CHUNK; i += 512) {
    int e = e0 + i;
    int d = dst[e];
    unsigned int sh = (d & 1) * 16;
    unsigned int old = atomicAdd(&h32[d >> 1], 1u << sh);
    rank16[(size_t)et * N_EDGES + e] = (unsigned short)((old >> sh) & 0xFFFFu);
  }
  __syncthreads();
  unsigned short* gh = ghist + ((size_t)(et * NB + b)) * N_NODES;
  for (int d = tid; d < N_NODES; d += 512)
    gh[d] = (unsigned short)((h32[d >> 1] >> ((d & 1) * 16)) & 0xFFFFu);
}

// ============== pass 2: per-dst exclusive prefix over NB blocks + totals ==============
__global__ __launch_bounds__(256)
void blockpfx_kernel(unsigned short* __restrict__ ghist, int* __restrict__ counts)
{
  int d = blockIdx.x * 256 + threadIdx.x;
  int et = blockIdx.y;
  if (d >= N_NODES) return;
  int running = 0;
#pragma unroll
  for (int b = 0; b < NB; ++b) {
    size_t idx = ((size_t)(et * NB + b)) * N_NODES + d;
    int v = ghist[idx];
    ghist[idx] = (unsigned short)running;
    running += v;
  }
  counts[et * N_NODES + d] = running;
}

// ============== batched scan (blockIdx.x = etype) ==============
__global__ __launch_bounds__(1024)
void scan_kernel(int* __restrict__ cc_all, int* __restrict__ off_all, int n, int total)
{
  int et = blockIdx.x;
  int* cc = cc_all + (size_t)et * n;
  int* off = off_all + (size_t)et * (n + 1);
  __shared__ int wsum[16];
  __shared__ int woff[16];
  __shared__ int s_carry, s_chunk;
  int tid = threadIdx.x;
  int lane = tid & 63, wid = tid >> 6;
  if (tid == 0) s_carry = 0;
  __syncthreads();
  for (int base = 0; base < n; base += 1024) {
    int i = base + tid;
    int v = (i < n) ? cc[i] : 0;
    int x = v;
#pragma unroll
    for (int s = 1; s < 64; s <<= 1) {
      int y = __shfl_up(x, s, 64);
      if (lane >= s) x += y;
    }
    if (lane == 63) wsum[wid] = x;
    __syncthreads();
    if (wid == 0 && lane < 16) {
      int ws_ = wsum[lane];
      int xx = ws_;
#pragma unroll
      for (int s = 1; s < 16; s <<= 1) {
        int y = __shfl_up(xx, s, 64);
        if (lane >= s) xx += y;
      }
      woff[lane] = xx - ws_;
      if (lane == 15) s_chunk = xx;
    }
    __syncthreads();
    int excl = s_carry + woff[wid] + (x - v);
    if (i < n) { off[i] = excl; cc[i] = excl; }
    __syncthreads();
    if (tid == 0) s_carry += s_chunk;
    __syncthreads();
  }
  if (tid == 0) off[n] = total;
}

// ============== pass 4: place packed payload (no atomics, single 8B scatter) ==============
__global__ __launch_bounds__(256)
void place_kernel(const int* __restrict__ d0, const int* __restrict__ d1,
                  const int* __restrict__ d2,
                  const int* __restrict__ s0, const int* __restrict__ s1,
                  const int* __restrict__ s2,
                  const float* __restrict__ w0, const float* __restrict__ w1,
                  const float* __restrict__ w2,
                  const int* __restrict__ off, const unsigned short* __restrict__ ghist,
                  const unsigned short* __restrict__ rank16,
                  int2* __restrict__ csr_pay)
{
  int e = blockIdx.x * 256 + threadIdx.x;
  if (e >= N_EDGES) return;
  int et = blockIdx.y;
  const int* dst = (et == 0) ? d0 : (et == 1) ? d1 : d2;
  const int* src = (et == 0) ? s0 : (et == 1) ? s1 : s2;
  const float* ew = (et == 0) ? w0 : (et == 1) ? w1 : w2;
  int d = dst[e];
  int b = e / CHUNK;
  int pos = off[et * (N_NODES + 1) + d]
          + (int)ghist[((size_t)(et * NB + b)) * N_NODES + d]
          + (int)rank16[(size_t)et * N_EDGES + e];
  csr_pay[(size_t)et * N_EDGES + pos] = make_int2(src[e], __float_as_int(ew[e]));
}

// ============== wave-per-node aggregation (barrier-free, 8 nodes/block) + fused gt/gb ==============
__global__ __launch_bounds__(512)
void aggregate_kernel(const int* __restrict__ off, const int2* __restrict__ csr_pay,
                      const float* __restrict__ el, const float* __restrict__ er,
                      const __half* __restrict__ feat, const float* __restrict__ bias,
                      const float* __restrict__ Wt, const float* __restrict__ Wb,
                      __half* __restrict__ gat, float* __restrict__ gt, float* __restrict__ gb,
                      int n_nodes)
{
  int tid = threadIdx.x;
  int lane = tid & 63, wv = tid >> 6;   // 8 waves per block
  int n = blockIdx.x * 8 + wv;
  if (n >= n_nodes) return;
  int hd = lane >> 4;                    // head of this lane's 4-column slice

  __shared__ int   s_src[8][16];
  __shared__ float s_cf[8][16][4];       // ex * ew
  __shared__ float s_ex[8][16][4];       // ex (for denom)

  int e0 = off[n], e1 = off[n + 1];
  float4 er4 = *(const float4*)&er[(size_t)n * 4];
  float4 bv = *(const float4*)&bias[lane * 4];
  float ac0 = 0.f, ac1 = 0.f, ac2 = 0.f, ac3 = 0.f, dn = 0.f;

  for (int base = e0; base < e1; base += 16) {
    int cnt = min(16, e1 - base);
    if (lane < cnt) {
      int2 pay = csr_pay[base + lane];
      int s = pay.x;
      float w = __int_as_float(pay.y);
      s_src[wv][lane] = s;
      float4 l4 = *(const float4*)&el[(size_t)s * 4];
      float v0 = l4.x + er4.x; v0 = v0 > 0.f ? v0 : 0.2f * v0;
      float v1 = l4.y + er4.y; v1 = v1 > 0.f ? v1 : 0.2f * v1;
      float v2 = l4.z + er4.z; v2 = v2 > 0.f ? v2 : 0.2f * v2;
      float v3 = l4.w + er4.w; v3 = v3 > 0.f ? v3 : 0.2f * v3;
      float x0 = __expf(v0), x1 = __expf(v1), x2 = __expf(v2), x3 = __expf(v3);
      s_ex[wv][lane][0] = x0; s_ex[wv][lane][1] = x1;
      s_ex[wv][lane][2] = x2; s_ex[wv][lane][3] = x3;
      s_cf[wv][lane][0] = x0 * w; s_cf[wv][lane][1] = x1 * w;
      s_cf[wv][lane][2] = x2 * w; s_cf[wv][lane][3] = x3 * w;
    }
    __builtin_amdgcn_wave_barrier();   // wave-synchronous: order LDS write->read
    int k = 0;
    for (; k + 3 < cnt; k += 4) {
      int sA = s_src[wv][k], sB = s_src[wv][k + 1], sC = s_src[wv][k + 2], sD = s_src[wv][k + 3];
      float cA = s_cf[wv][k][hd], cB = s_cf[wv][k + 1][hd];
      float cC = s_cf[wv][k + 2][hd], cD = s_cf[wv][k + 3][hd];
      dn += s_ex[wv][k][hd] + s_ex[wv][k + 1][hd] + s_ex[wv][k + 2][hd] + s_ex[wv][k + 3][hd];
      uint2 uA = *(const uint2*)(feat + (size_t)sA * 256 + lane * 4);
      uint2 uB = *(const uint2*)(feat + (size_t)sB * 256 + lane * 4);
      uint2 uC = *(const uint2*)(feat + (size_t)sC * 256 + lane * 4);
      uint2 uD = *(const uint2*)(feat + (size_t)sD * 256 + lane * 4);
      float2 A01 = __half22float2(*(__half2*)&uA.x), A23 = __half22float2(*(__half2*)&uA.y);
      float2 B01 = __half22float2(*(__half2*)&uB.x), B23 = __half22float2(*(__half2*)&uB.y);
      float2 C01 = __half22float2(*(__half2*)&uC.x), C23 = __half22float2(*(__half2*)&uC.y);
      float2 D01 = __half22float2(*(__half2*)&uD.x), D23 = __half22float2(*(__half2*)&uD.y);
      ac0 = fmaf(cA, A01.x, ac0); ac1 = fmaf(cA, A01.y, ac1);
      ac2 = fmaf(cA, A23.x, ac2); ac3 = fmaf(cA, A23.y, ac3);
      ac0 = fmaf(cB, B01.x, ac0); ac1 = fmaf(cB, B01.y, ac1);
      ac2 = fmaf(cB, B23.x, ac2); ac3 = fmaf(cB, B23.y, ac3);
      ac0 = fmaf(cC, C01.x, ac0); ac1 = fmaf(cC, C01.y, ac1);
      ac2 = fmaf(cC, C23.x, ac2); ac3 = fmaf(cC, C23.y, ac3);
      ac0 = fmaf(cD, D01.x, ac0); ac1 = fmaf(cD, D01.y, ac1);
      ac2 = fmaf(cD, D23.x, ac2); ac3 = fmaf(cD, D23.y, ac3);
    }
    for (; k < cnt; ++k) {
      int s0 = s_src[wv][k];
      float c0 = s_cf[wv][k][hd];
      dn += s_ex[wv][k][hd];
      uint2 u = *(const uint2*)(feat + (size_t)s0 * 256 + lane * 4);
      float2 f01 = __half22float2(*(__half2*)&u.x), f23 = __half22float2(*(__half2*)&u.y);
      ac0 = fmaf(c0, f01.x, ac0); ac1 = fmaf(c0, f01.y, ac1);
      ac2 = fmaf(c0, f23.x, ac2); ac3 = fmaf(c0, f23.y, ac3);
    }
    __builtin_amdgcn_wave_barrier();   // don't let next chunk's writes sink above these reads
  }

  float invd = (dn != 0.f) ? 1.f / dn : 0.f;
  float v0 = ac0 * invd + bv.x;
  float v1 = ac1 * invd + bv.y;
  float v2 = ac2 * invd + bv.z;
  float v3 = ac3 * invd + bv.w;

  __half2 h01 = __floats2half2_rn(v0, v1);
  __half2 h23 = __floats2half2_rn(v2, v3);
  uint2 st;
  st.x = *(unsigned int*)&h01;
  st.y = *(unsigned int*)&h23;
  *(uint2*)&gat[(size_t)n * 256 + lane * 4] = st;

  // fused projection: p[0..7] = gt partials, p[8..15] = gb partials (in-wave)
  float p[16];
#pragma unroll
  for (int j = 0; j < 16; ++j) p[j] = 0.f;
  float fv[4] = {v0, v1, v2, v3};
#pragma unroll
  for (int r = 0; r < 4; ++r) {
    int c = lane * 4 + r;
    const float* wtr = &Wt[(size_t)c * 8];
    const float* wbr = &Wb[(size_t)c * 8];
#pragma unroll
    for (int j = 0; j < 8; ++j) {
      p[j]     = fmaf(fv[r], wtr[j], p[j]);
      p[8 + j] = fmaf(fv[r], wbr[j], p[8 + j]);
    }
  }
#pragma unroll
  for (int o = 32; o >= 1; o >>= 1) {
#pragma unroll
    for (int j = 0; j < 16; ++j) p[j] += __shfl_xor(p[j], o, 64);
  }
  if (lane == 0) {
#pragma unroll
    for (int j = 0; j < 8; ++j) {
      gt[(size_t)n * 8 + j] = p[j];
      gb[(size_t)n * 8 + j] = p[8 + j];
    }
  }
}

// ============== enhance: wave-per-node; rank + tiny gt/gb gathers ==============
__global__ __launch_bounds__(256)
void enhance_pool_kernel(const int* __restrict__ nbr_idx, const float* __restrict__ nbr_w,
                         const float* __restrict__ gt, const float* __restrict__ gb,
                         const float* __restrict__ bt, const float* __restrict__ bb,
                         float* __restrict__ tvec, float* __restrict__ bvec, int n_nodes)
{
  int n = (blockIdx.x * 256 + threadIdx.x) >> 6;
  int lane = threadIdx.x & 63;
  if (n >= n_nodes) return;
  const int l16 = lane & 15;

  float w = nbr_w[(size_t)n * 16 + l16];
  int idx = nbr_idx[(size_t)n * 16 + l16];

  int rhi = 0, rlo = 0;
#pragma unroll
  for (int i = 0; i < 16; ++i) {
    float wi = __shfl(w, i, 64);
    rhi += (wi > w) || (wi == w && i < l16);
    rlo += (wi < w) || (wi == w && i < l16);
  }

  int rows[7];
#pragma unroll
  for (int q = 0; q < 5; ++q) {
    unsigned long long m = __ballot(lane < 16 && rhi == q);
    rows[q] = __shfl(idx, __ffsll(m) - 1, 64);
  }
#pragma unroll
  for (int q = 0; q < 2; ++q) {
    unsigned long long m = __ballot(lane < 16 && rlo == q);
    rows[5 + q] = __shfl(idx, __ffsll(m) - 1, 64);
  }

  int j = lane & 7;
  if (lane < 8) {
    float s = 0.f;
#pragma unroll
    for (int q = 0; q < 5; ++q) s += gt[(size_t)rows[q] * 8 + j];
    tvec[(size_t)n * 8 + j] = s * 0.2f + bt[j];
  } else if (lane < 16) {
    float s = gb[(size_t)rows[5] * 8 + j] + gb[(size_t)rows[6] * 8 + j];
    bvec[(size_t)n * 8 + j] = s * 0.5f + bb[j];
  }
}

extern "C" void kernel_launch(void* const* d_in, const int* in_sizes, int n_in,
                              void* d_out, int out_size, void* d_ws, size_t ws_size,
                              hipStream_t stream)
{
  const int N_ = N_NODES;
  const int E_ = N_EDGES;

  const float* h = (const float*)d_in[0];
  const float* Wt = (const float*)d_in[28];
  const float* bt = (const float*)d_in[29];
  const float* Wb = (const float*)d_in[30];
  const float* bb = (const float*)d_in[31];
  const float* Wp = (const float*)d_in[32];
  const float* bp = (const float*)d_in[33];
  float* out = (float*)d_out;

  char* wsb = (char*)d_ws;
  size_t o = 0;
  auto alloc = [&](size_t bytes) -> void* {
    void* p = wsb + o;
    o = (o + bytes + 255) & ~(size_t)255;
    return p;
  };
  f16*  hf    = (f16*)alloc((size_t)N_ * 256 * 2);
  f16*  feat  = (f16*)alloc((size_t)N_ * 256 * 2);
  f16*  gat   = (f16*)alloc((size_t)N_ * 256 * 2);
  f16*  WT    = (f16*)alloc((size_t)4 * 256 * 256 * 2);   // 3x W + WpT
  float* el     = (float*)alloc((size_t)N_ * 4 * 4);
  float* er     = (float*)alloc((size_t)N_ * 4 * 4);
  float* gt     = (float*)alloc((size_t)N_ * 8 * 4);
  float* gb     = (float*)alloc((size_t)N_ * 8 * 4);
  float* tvec   = (float*)alloc((size_t)N_ * 8 * 4);
  float* bvec   = (float*)alloc((size_t)N_ * 8 * 4);
  int*   off    = (int*)alloc((size_t)3 * (N_ + 1) * 4);
  int*   counts = (int*)alloc((size_t)3 * N_ * 4);
  unsigned short* ghist = (unsigned short*)alloc((size_t)3 * NB * N_ * 2);  // 11.5 MB
  unsigned short* rank16 = (unsigned short*)alloc((size_t)3 * E_ * 2);
  int2*  csr_pay = (int2*)alloc((size_t)3 * E_ * 8);
  (void)ws_size; (void)in_sizes; (void)n_in; (void)out_size;

  const int row_blocks = (N_ + 127) / 128;  // 235
  const int edge_blocks = (E_ + 255) / 256; // 1875
  const int wave_blocks = (N_ + 3) / 4;     // 7500 (enhance)
  const int agg_blocks = (N_ + 7) / 8;      // 3750 (aggregate, 8 nodes/block)

  const int* d_dst0 = (const int*)d_in[1 + 0 * 9 + 1];
  const int* d_dst1 = (const int*)d_in[1 + 1 * 9 + 1];
  const int* d_dst2 = (const int*)d_in[1 + 2 * 9 + 1];
  const int* d_src0 = (const int*)d_in[1 + 0 * 9 + 0];
  const int* d_src1 = (const int*)d_in[1 + 1 * 9 + 0];
  const int* d_src2 = (const int*)d_in[1 + 2 * 9 + 0];
  const float* d_ew0 = (const float*)d_in[1 + 0 * 9 + 2];
  const float* d_ew1 = (const float*)d_in[1 + 1 * 9 + 2];
  const float* d_ew2 = (const float*)d_in[1 + 2 * 9 + 2];

  // one-time conversions (independent of CSR build)
  convert_h_kernel<<<(N_ * 256 / 8 + 255) / 256, 256, 0, stream>>>(h, hf, N_ * 256 / 8);
  transpose_w_kernel<<<dim3(256, 4), 256, 0, stream>>>(
      (const float*)d_in[1 + 0 * 9 + 5], (const float*)d_in[1 + 1 * 9 + 5],
      (const float*)d_in[1 + 2 * 9 + 5], Wp, WT);
  f16* WpT = WT + (size_t)3 * 65536;

  // atomic-free CSR build (batched over etypes)
  hist_kernel<<<dim3(NB, 3), 512, 0, stream>>>(d_dst0, d_dst1, d_dst2, ghist, rank16);
  blockpfx_kernel<<<dim3((N_ + 255) / 256, 3), 256, 0, stream>>>(ghist, counts);
  scan_kernel<<<3, 1024, 0, stream>>>(counts, off, N_, E_);
  place_kernel<<<dim3(edge_blocks, 3), 256, 0, stream>>>(
      d_dst0, d_dst1, d_dst2, d_src0, d_src1, d_src2, d_ew0, d_ew1, d_ew2,
      off, ghist, rank16, csr_pay);

  for (int et = 0; et < 3; ++et) {
    const int base = 1 + et * 9;
    const int* nbr_idx = (const int*)d_in[base + 3];
    const float* nbr_w = (const float*)d_in[base + 4];
    const float* al = (const float*)d_in[base + 6];
    const float* ar = (const float*)d_in[base + 7];
    const float* b = (const float*)d_in[base + 8];

    gemm_mfma<0><<<dim3(row_blocks, 4), 256, 0, stream>>>(
        hf, WT + (size_t)et * 65536, feat, nullptr, N_, al, ar, el, er,
        nullptr, nullptr, nullptr, nullptr, nullptr, 256, 0);

    aggregate_kernel<<<agg_blocks, 512, 0, stream>>>(
        off + (size_t)et * (N_ + 1), csr_pay + (size_t)et * E_,
        el, er, (const __half*)feat, b, Wt, Wb, (__half*)gat, gt, gb, N_);

    enhance_pool_kernel<<<wave_blocks, 256, 0, stream>>>(
        nbr_idx, nbr_w, gt, gb, bt, bb, tvec, bvec, N_);

    gemm_mfma<1><<<dim3(row_blocks, 4), 256, 0, stream>>>(
        gat, WpT, nullptr, out, N_, nullptr, nullptr, nullptr, nullptr,
        tvec, bvec, Wp + 256 * 256, Wp + 264 * 256, bp, 768, et * 256);
  }
}

// Round 12
// 456.227 us; speedup vs baseline: 1.1619x; 1.1149x over previous
//
#include <hip/hip_runtime.h>
#include <hip/hip_fp16.h>

#define N_NODES 30000
#define N_EDGES 480000
#define NB 64           // blocks per etype for counting sort
#define CHUNK 7500      // N_EDGES / NB  (< 65536 so u16 ranks/counts are safe)

typedef _Float16 f16;
typedef f16 f16x8 __attribute__((ext_vector_type(8)));
typedef float f32x4 __attribute__((ext_vector_type(4)));

// ================= one-time converts =================
__global__ void convert_h_kernel(const float* __restrict__ in, f16* __restrict__ out, int n8)
{
  int i = blockIdx.x * 256 + threadIdx.x;
  if (i >= n8) return;
  float4 a = *(const float4*)(in + (size_t)i * 8);
  float4 b = *(const float4*)(in + (size_t)i * 8 + 4);
  f16x8 v;
  v[0] = (f16)a.x; v[1] = (f16)a.y; v[2] = (f16)a.z; v[3] = (f16)a.w;
  v[4] = (f16)b.x; v[5] = (f16)b.y; v[6] = (f16)b.z; v[7] = (f16)b.w;
  *(f16x8*)(out + (size_t)i * 8) = v;
}

// out[m][n][k] = (f16) in_m[k][n], 4 matrices 256x256, blockIdx.y = m
__global__ void transpose_w_kernel(const float* __restrict__ s0, const float* __restrict__ s1,
                                   const float* __restrict__ s2, const float* __restrict__ s3,
                                   f16* __restrict__ out)
{
  int m = blockIdx.y;
  const float* in = (m == 0) ? s0 : (m == 1) ? s1 : (m == 2) ? s2 : s3;
  int t = blockIdx.x * 256 + threadIdx.x;   // 65536
  int n = t >> 8, k = t & 255;
  out[(size_t)m * 65536 + t] = (f16)in[k * 256 + n];
}

// W12T[col][k] (f16, [256][40]): k<8 -> Wp1[k][col], k<16 -> Wp2[k-8][col], else 0
__global__ void w12_kernel(const float* __restrict__ Wp, f16* __restrict__ W12T)
{
  int t = blockIdx.x * 256 + threadIdx.x;   // 10240
  if (t >= 256 * 40) return;
  int col = t / 40, k = t % 40;
  f16 v = (f16)0.f;
  if (k < 8)       v = (f16)Wp[(size_t)(256 + k) * 256 + col];
  else if (k < 16) v = (f16)Wp[(size_t)(264 + (k - 8)) * 256 + col];
  W12T[t] = v;
}

// ================= MFMA GEMM: 128 rows x FULL 256 cols, whole B in LDS =================
// 512 threads = 8 waves (4 row x 2 col); wave = 32 rows x 128 cols.
// MODE 0: feat(f16) = A@B; epilogue el/er (2 heads per wave)
// MODE 1: out(f32) = A@B + t@Wp1 + bo@Wp2 + bp via one extra MFMA; strided store
template<int MODE>
__global__ __launch_bounds__(512)
void gemm_mfma(const f16* __restrict__ A, const f16* __restrict__ BT,
               f16* __restrict__ Ch, float* __restrict__ Cf, int M,
               const float* __restrict__ al, const float* __restrict__ ar,
               float* __restrict__ el, float* __restrict__ er,
               const float* __restrict__ tvec, const float* __restrict__ bvec,
               const f16* __restrict__ W12Tg, const float* __restrict__ bp,
               int ldc, int coff)
{
  __shared__ alignas(16) f16 Bs[256][264];                  // 135 KB, 16B-aligned rows
  __shared__ alignas(16) f16 W12s[MODE ? 256 : 1][MODE ? 40 : 8];  // 20 KB (MODE 1)

  const int tid = threadIdx.x;
  const int lane = tid & 63, wv = tid >> 6;
  const int l15 = lane & 15, lq = lane >> 4;
  const int wr = wv >> 1, wc = wv & 1;
  const int bm = blockIdx.x * 128;
  const int cb = wc * 128;

  // stage full BT: 256 cols x 256 k = 8192 uint4, 16 per thread
#pragma unroll
  for (int i = 0; i < 16; ++i) {
    int seg = tid + i * 512;
    int row = seg >> 5;
    int cs = (seg & 31) * 8;
    *(uint4*)&Bs[row][cs] = *(const uint4*)&BT[(size_t)row * 256 + cs];
  }
  if (MODE == 1) {
    // stage W12T: 10240 f16 = 2560 uint2
    for (int i = tid; i < 2560; i += 512)
      ((uint2*)&W12s[0][0])[i] = ((const uint2*)W12Tg)[i];
  }
  __syncthreads();

  const int r0 = bm + wr * 32 + l15;
  const int r1 = r0 + 16;
  const bool ok0 = r0 < M, ok1 = r1 < M;
  const f16* Arow0 = A + (size_t)r0 * 256;
  const f16* Arow1 = A + (size_t)r1 * 256;

  f32x4 acc[2][8] = {};

#pragma unroll
  for (int k0 = 0; k0 < 256; k0 += 32) {
    int ko = k0 + lq * 8;
    f16x8 a0 = {0, 0, 0, 0, 0, 0, 0, 0};
    f16x8 a1 = {0, 0, 0, 0, 0, 0, 0, 0};
    if (ok0) a0 = *(const f16x8*)(Arow0 + ko);
    if (ok1) a1 = *(const f16x8*)(Arow1 + ko);
#pragma unroll
    for (int nf = 0; nf < 8; ++nf) {
      f16x8 bf = *(const f16x8*)&Bs[cb + nf * 16 + l15][ko];
      acc[0][nf] = __builtin_amdgcn_mfma_f32_16x16x32_f16(a0, bf, acc[0][nf], 0, 0, 0);
      acc[1][nf] = __builtin_amdgcn_mfma_f32_16x16x32_f16(a1, bf, acc[1][nf], 0, 0, 0);
    }
  }

  if (MODE == 0) {
    float alv[8], arv[8];
#pragma unroll
    for (int nf = 0; nf < 8; ++nf) {
      alv[nf] = al[cb + nf * 16 + l15];
      arv[nf] = ar[cb + nf * 16 + l15];
    }
#pragma unroll
    for (int m = 0; m < 2; ++m)
#pragma unroll
      for (int i = 0; i < 4; ++i) {
        int row = bm + wr * 32 + m * 16 + lq * 4 + i;
        float peA = 0.f, prA = 0.f, peB = 0.f, prB = 0.f;
#pragma unroll
        for (int nf = 0; nf < 4; ++nf) {
          peA = fmaf(acc[m][nf][i], alv[nf], peA);
          prA = fmaf(acc[m][nf][i], arv[nf], prA);
          peB = fmaf(acc[m][nf + 4][i], alv[nf + 4], peB);
          prB = fmaf(acc[m][nf + 4][i], arv[nf + 4], prB);
        }
#pragma unroll
        for (int o = 8; o >= 1; o >>= 1) {
          peA += __shfl_xor(peA, o, 64);
          prA += __shfl_xor(prA, o, 64);
          peB += __shfl_xor(peB, o, 64);
          prB += __shfl_xor(prB, o, 64);
        }
        if (row < M) {
          if (l15 == 0) {
            int hA = wc * 2;
            el[row * 4 + hA] = peA;     er[row * 4 + hA] = prA;
            el[row * 4 + hA + 1] = peB; er[row * 4 + hA + 1] = prB;
          }
#pragma unroll
          for (int nf = 0; nf < 8; ++nf)
            Ch[(size_t)row * 256 + cb + nf * 16 + l15] = (f16)acc[m][nf][i];
        }
      }
  } else {
    // rank-8 correction via one MFMA per (m, nf): A-frag = [t(8), bo(8), 0(16)]
#pragma unroll
    for (int m = 0; m < 2; ++m) {
      int arow = bm + wr * 32 + m * 16 + l15;
      f16x8 af = {0, 0, 0, 0, 0, 0, 0, 0};
      if (arow < M && lq < 2) {
        const float* srcp = (lq == 0) ? &tvec[(size_t)arow * 8] : &bvec[(size_t)arow * 8];
        float4 x0 = *(const float4*)srcp;
        float4 x1 = *(const float4*)(srcp + 4);
        af[0] = (f16)x0.x; af[1] = (f16)x0.y; af[2] = (f16)x0.z; af[3] = (f16)x0.w;
        af[4] = (f16)x1.x; af[5] = (f16)x1.y; af[6] = (f16)x1.z; af[7] = (f16)x1.w;
      }
#pragma unroll
      for (int nf = 0; nf < 8; ++nf) {
        f16x8 bf2 = *(const f16x8*)&W12s[cb + nf * 16 + l15][lq * 8];
        acc[m][nf] = __builtin_amdgcn_mfma_f32_16x16x32_f16(af, bf2, acc[m][nf], 0, 0, 0);
      }
    }
    float bpv[8];
#pragma unroll
    for (int nf = 0; nf < 8; ++nf) bpv[nf] = bp[cb + nf * 16 + l15];
#pragma unroll
    for (int m = 0; m < 2; ++m)
#pragma unroll
      for (int i = 0; i < 4; ++i) {
        int row = bm + wr * 32 + m * 16 + lq * 4 + i;
        if (row >= M) continue;
#pragma unroll
        for (int nf = 0; nf < 8; ++nf)
          Cf[(size_t)row * ldc + coff + cb + nf * 16 + l15] = acc[m][nf][i] + bpv[nf];
      }
  }
}

// ============== CSR build pass 1: LDS histogram + per-edge local rank ==============
__global__ __launch_bounds__(512)
void hist_kernel(const int* __restrict__ d0, const int* __restrict__ d1,
                 const int* __restrict__ d2, unsigned short* __restrict__ ghist,
                 unsigned short* __restrict__ rank16)
{
  __shared__ unsigned int h32[N_NODES / 2];
  int et = blockIdx.y, b = blockIdx.x, tid = threadIdx.x;
  const int* dst = (et == 0) ? d0 : (et == 1) ? d1 : d2;
  for (int i = tid; i < N_NODES / 2; i += 512) h32[i] = 0u;
  __syncthreads();
  int e0 = b * CHUNK;
  for (int i = tid; i < CHUNK; i += 512) {
    int e = e0 + i;
    int d = dst[e];
    unsigned int sh = (d & 1) * 16;
    unsigned int old = atomicAdd(&h32[d >> 1], 1u << sh);
    rank16[(size_t)et * N_EDGES + e] = (unsigned short)((old >> sh) & 0xFFFFu);
  }
  __syncthreads();
  unsigned short* gh = ghist + ((size_t)(et * NB + b)) * N_NODES;
  for (int d = tid; d < N_NODES; d += 512)
    gh[d] = (unsigned short)((h32[d >> 1] >> ((d & 1) * 16)) & 0xFFFFu);
}

// ============== pass 2: per-dst exclusive prefix over NB blocks + totals ==============
__global__ __launch_bounds__(256)
void blockpfx_kernel(unsigned short* __restrict__ ghist, int* __restrict__ counts)
{
  int d = blockIdx.x * 256 + threadIdx.x;
  int et = blockIdx.y;
  if (d >= N_NODES) return;
  int running = 0;
#pragma unroll
  for (int b = 0; b < NB; ++b) {
    size_t idx = ((size_t)(et * NB + b)) * N_NODES + d;
    int v = ghist[idx];
    ghist[idx] = (unsigned short)running;
    running += v;
  }
  counts[et * N_NODES + d] = running;
}

// ============== batched scan (blockIdx.x = etype) ==============
__global__ __launch_bounds__(1024)
void scan_kernel(int* __restrict__ cc_all, int* __restrict__ off_all, int n, int total)
{
  int et = blockIdx.x;
  int* cc = cc_all + (size_t)et * n;
  int* off = off_all + (size_t)et * (n + 1);
  __shared__ int wsum[16];
  __shared__ int woff[16];
  __shared__ int s_carry, s_chunk;
  int tid = threadIdx.x;
  int lane = tid & 63, wid = tid >> 6;
  if (tid == 0) s_carry = 0;
  __syncthreads();
  for (int base = 0; base < n; base += 1024) {
    int i = base + tid;
    int v = (i < n) ? cc[i] : 0;
    int x = v;
#pragma unroll
    for (int s = 1; s < 64; s <<= 1) {
      int y = __shfl_up(x, s, 64);
      if (lane >= s) x += y;
    }
    if (lane == 63) wsum[wid] = x;
    __syncthreads();
    if (wid == 0 && lane < 16) {
      int ws_ = wsum[lane];
      int xx = ws_;
#pragma unroll
      for (int s = 1; s < 16; s <<= 1) {
        int y = __shfl_up(xx, s, 64);
        if (lane >= s) xx += y;
      }
      woff[lane] = xx - ws_;
      if (lane == 15) s_chunk = xx;
    }
    __syncthreads();
    int excl = s_carry + woff[wid] + (x - v);
    if (i < n) { off[i] = excl; cc[i] = excl; }
    __syncthreads();
    if (tid == 0) s_carry += s_chunk;
    __syncthreads();
  }
  if (tid == 0) off[n] = total;
}

// ============== pass 4: place packed payload (no atomics, single 8B scatter) ==============
__global__ __launch_bounds__(256)
void place_kernel(const int* __restrict__ d0, const int* __restrict__ d1,
                  const int* __restrict__ d2,
                  const int* __restrict__ s0, const int* __restrict__ s1,
                  const int* __restrict__ s2,
                  const float* __restrict__ w0, const float* __restrict__ w1,
                  const float* __restrict__ w2,
                  const int* __restrict__ off, const unsigned short* __restrict__ ghist,
                  const unsigned short* __restrict__ rank16,
                  int2* __restrict__ csr_pay)
{
  int e = blockIdx.x * 256 + threadIdx.x;
  if (e >= N_EDGES) return;
  int et = blockIdx.y;
  const int* dst = (et == 0) ? d0 : (et == 1) ? d1 : d2;
  const int* src = (et == 0) ? s0 : (et == 1) ? s1 : s2;
  const float* ew = (et == 0) ? w0 : (et == 1) ? w1 : w2;
  int d = dst[e];
  int b = e / CHUNK;
  int pos = off[et * (N_NODES + 1) + d]
          + (int)ghist[((size_t)(et * NB + b)) * N_NODES + d]
          + (int)rank16[(size_t)et * N_EDGES + e];
  csr_pay[(size_t)et * N_EDGES + pos] = make_int2(src[e], __float_as_int(ew[e]));
}

// ============== wave-per-node aggregation (barrier-free, 8 nodes/block) + fused gt/gb ==============
__global__ __launch_bounds__(512)
void aggregate_kernel(const int* __restrict__ off, const int2* __restrict__ csr_pay,
                      const float* __restrict__ el, const float* __restrict__ er,
                      const __half* __restrict__ feat, const float* __restrict__ bias,
                      const float* __restrict__ Wt, const float* __restrict__ Wb,
                      __half* __restrict__ gat, float* __restrict__ gt, float* __restrict__ gb,
                      int n_nodes)
{
  int tid = threadIdx.x;
  int lane = tid & 63, wv = tid >> 6;   // 8 waves per block
  int n = blockIdx.x * 8 + wv;
  if (n >= n_nodes) return;
  int hd = lane >> 4;

  __shared__ int   s_src[8][16];
  __shared__ float s_cf[8][16][4];
  __shared__ float s_ex[8][16][4];

  int e0 = off[n], e1 = off[n + 1];
  float4 er4 = *(const float4*)&er[(size_t)n * 4];
  float4 bv = *(const float4*)&bias[lane * 4];
  float ac0 = 0.f, ac1 = 0.f, ac2 = 0.f, ac3 = 0.f, dn = 0.f;

  for (int base = e0; base < e1; base += 16) {
    int cnt = min(16, e1 - base);
    if (lane < cnt) {
      int2 pay = csr_pay[base + lane];
      int s = pay.x;
      float w = __int_as_float(pay.y);
      s_src[wv][lane] = s;
      float4 l4 = *(const float4*)&el[(size_t)s * 4];
      float v0 = l4.x + er4.x; v0 = v0 > 0.f ? v0 : 0.2f * v0;
      float v1 = l4.y + er4.y; v1 = v1 > 0.f ? v1 : 0.2f * v1;
      float v2 = l4.z + er4.z; v2 = v2 > 0.f ? v2 : 0.2f * v2;
      float v3 = l4.w + er4.w; v3 = v3 > 0.f ? v3 : 0.2f * v3;
      float x0 = __expf(v0), x1 = __expf(v1), x2 = __expf(v2), x3 = __expf(v3);
      s_ex[wv][lane][0] = x0; s_ex[wv][lane][1] = x1;
      s_ex[wv][lane][2] = x2; s_ex[wv][lane][3] = x3;
      s_cf[wv][lane][0] = x0 * w; s_cf[wv][lane][1] = x1 * w;
      s_cf[wv][lane][2] = x2 * w; s_cf[wv][lane][3] = x3 * w;
    }
    __builtin_amdgcn_wave_barrier();
    int k = 0;
    for (; k + 3 < cnt; k += 4) {
      int sA = s_src[wv][k], sB = s_src[wv][k + 1], sC = s_src[wv][k + 2], sD = s_src[wv][k + 3];
      float cA = s_cf[wv][k][hd], cB = s_cf[wv][k + 1][hd];
      float cC = s_cf[wv][k + 2][hd], cD = s_cf[wv][k + 3][hd];
      dn += s_ex[wv][k][hd] + s_ex[wv][k + 1][hd] + s_ex[wv][k + 2][hd] + s_ex[wv][k + 3][hd];
      uint2 uA = *(const uint2*)(feat + (size_t)sA * 256 + lane * 4);
      uint2 uB = *(const uint2*)(feat + (size_t)sB * 256 + lane * 4);
      uint2 uC = *(const uint2*)(feat + (size_t)sC * 256 + lane * 4);
      uint2 uD = *(const uint2*)(feat + (size_t)sD * 256 + lane * 4);
      float2 A01 = __half22float2(*(__half2*)&uA.x), A23 = __half22float2(*(__half2*)&uA.y);
      float2 B01 = __half22float2(*(__half2*)&uB.x), B23 = __half22float2(*(__half2*)&uB.y);
      float2 C01 = __half22float2(*(__half2*)&uC.x), C23 = __half22float2(*(__half2*)&uC.y);
      float2 D01 = __half22float2(*(__half2*)&uD.x), D23 = __half22float2(*(__half2*)&uD.y);
      ac0 = fmaf(cA, A01.x, ac0); ac1 = fmaf(cA, A01.y, ac1);
      ac2 = fmaf(cA, A23.x, ac2); ac3 = fmaf(cA, A23.y, ac3);
      ac0 = fmaf(cB, B01.x, ac0); ac1 = fmaf(cB, B01.y, ac1);
      ac2 = fmaf(cB, B23.x, ac2); ac3 = fmaf(cB, B23.y, ac3);
      ac0 = fmaf(cC, C01.x, ac0); ac1 = fmaf(cC, C01.y, ac1);
      ac2 = fmaf(cC, C23.x, ac2); ac3 = fmaf(cC, C23.y, ac3);
      ac0 = fmaf(cD, D01.x, ac0); ac1 = fmaf(cD, D01.y, ac1);
      ac2 = fmaf(cD, D23.x, ac2); ac3 = fmaf(cD, D23.y, ac3);
    }
    for (; k < cnt; ++k) {
      int s0 = s_src[wv][k];
      float c0 = s_cf[wv][k][hd];
      dn += s_ex[wv][k][hd];
      uint2 u = *(const uint2*)(feat + (size_t)s0 * 256 + lane * 4);
      float2 f01 = __half22float2(*(__half2*)&u.x), f23 = __half22float2(*(__half2*)&u.y);
      ac0 = fmaf(c0, f01.x, ac0); ac1 = fmaf(c0, f01.y, ac1);
      ac2 = fmaf(c0, f23.x, ac2); ac3 = fmaf(c0, f23.y, ac3);
    }
    __builtin_amdgcn_wave_barrier();
  }

  float invd = (dn != 0.f) ? 1.f / dn : 0.f;
  float v0 = ac0 * invd + bv.x;
  float v1 = ac1 * invd + bv.y;
  float v2 = ac2 * invd + bv.z;
  float v3 = ac3 * invd + bv.w;

  __half2 h01 = __floats2half2_rn(v0, v1);
  __half2 h23 = __floats2half2_rn(v2, v3);
  uint2 st;
  st.x = *(unsigned int*)&h01;
  st.y = *(unsigned int*)&h23;
  *(uint2*)&gat[(size_t)n * 256 + lane * 4] = st;

  float p[16];
#pragma unroll
  for (int j = 0; j < 16; ++j) p[j] = 0.f;
  float fv[4] = {v0, v1, v2, v3};
#pragma unroll
  for (int r = 0; r < 4; ++r) {
    int c = lane * 4 + r;
    const float* wtr = &Wt[(size_t)c * 8];
    const float* wbr = &Wb[(size_t)c * 8];
#pragma unroll
    for (int j = 0; j < 8; ++j) {
      p[j]     = fmaf(fv[r], wtr[j], p[j]);
      p[8 + j] = fmaf(fv[r], wbr[j], p[8 + j]);
    }
  }
#pragma unroll
  for (int o = 32; o >= 1; o >>= 1) {
#pragma unroll
    for (int j = 0; j < 16; ++j) p[j] += __shfl_xor(p[j], o, 64);
  }
  if (lane == 0) {
#pragma unroll
    for (int j = 0; j < 8; ++j) {
      gt[(size_t)n * 8 + j] = p[j];
      gb[(size_t)n * 8 + j] = p[8 + j];
    }
  }
}

// ============== enhance: wave-per-node; rank + tiny gt/gb gathers ==============
__global__ __launch_bounds__(256)
void enhance_pool_kernel(const int* __restrict__ nbr_idx, const float* __restrict__ nbr_w,
                         const float* __restrict__ gt, const float* __restrict__ gb,
                         const float* __restrict__ bt, const float* __restrict__ bb,
                         float* __restrict__ tvec, float* __restrict__ bvec, int n_nodes)
{
  int n = (blockIdx.x * 256 + threadIdx.x) >> 6;
  int lane = threadIdx.x & 63;
  if (n >= n_nodes) return;
  const int l16 = lane & 15;

  float w = nbr_w[(size_t)n * 16 + l16];
  int idx = nbr_idx[(size_t)n * 16 + l16];

  int rhi = 0, rlo = 0;
#pragma unroll
  for (int i = 0; i < 16; ++i) {
    float wi = __shfl(w, i, 64);
    rhi += (wi > w) || (wi == w && i < l16);
    rlo += (wi < w) || (wi == w && i < l16);
  }

  int rows[7];
#pragma unroll
  for (int q = 0; q < 5; ++q) {
    unsigned long long m = __ballot(lane < 16 && rhi == q);
    rows[q] = __shfl(idx, __ffsll(m) - 1, 64);
  }
#pragma unroll
  for (int q = 0; q < 2; ++q) {
    unsigned long long m = __ballot(lane < 16 && rlo == q);
    rows[5 + q] = __shfl(idx, __ffsll(m) - 1, 64);
  }

  int j = lane & 7;
  if (lane < 8) {
    float s = 0.f;
#pragma unroll
    for (int q = 0; q < 5; ++q) s += gt[(size_t)rows[q] * 8 + j];
    tvec[(size_t)n * 8 + j] = s * 0.2f + bt[j];
  } else if (lane < 16) {
    float s = gb[(size_t)rows[5] * 8 + j] + gb[(size_t)rows[6] * 8 + j];
    bvec[(size_t)n * 8 + j] = s * 0.5f + bb[j];
  }
}

extern "C" void kernel_launch(void* const* d_in, const int* in_sizes, int n_in,
                              void* d_out, int out_size, void* d_ws, size_t ws_size,
                              hipStream_t stream)
{
  const int N_ = N_NODES;
  const int E_ = N_EDGES;

  const float* h = (const float*)d_in[0];
  const float* Wt = (const float*)d_in[28];
  const float* bt = (const float*)d_in[29];
  const float* Wb = (const float*)d_in[30];
  const float* bb = (const float*)d_in[31];
  const float* Wp = (const float*)d_in[32];
  const float* bp = (const float*)d_in[33];
  float* out = (float*)d_out;

  char* wsb = (char*)d_ws;
  size_t o = 0;
  auto alloc = [&](size_t bytes) -> void* {
    void* p = wsb + o;
    o = (o + bytes + 255) & ~(size_t)255;
    return p;
  };
  f16*  hf    = (f16*)alloc((size_t)N_ * 256 * 2);
  f16*  feat  = (f16*)alloc((size_t)N_ * 256 * 2);
  f16*  gat   = (f16*)alloc((size_t)N_ * 256 * 2);
  f16*  WT    = (f16*)alloc((size_t)4 * 256 * 256 * 2);   // 3x W + WpT
  f16*  W12T  = (f16*)alloc((size_t)256 * 40 * 2);
  float* el     = (float*)alloc((size_t)N_ * 4 * 4);
  float* er     = (float*)alloc((size_t)N_ * 4 * 4);
  float* gt     = (float*)alloc((size_t)N_ * 8 * 4);
  float* gb     = (float*)alloc((size_t)N_ * 8 * 4);
  float* tvec   = (float*)alloc((size_t)N_ * 8 * 4);
  float* bvec   = (float*)alloc((size_t)N_ * 8 * 4);
  int*   off    = (int*)alloc((size_t)3 * (N_ + 1) * 4);
  int*   counts = (int*)alloc((size_t)3 * N_ * 4);
  unsigned short* ghist = (unsigned short*)alloc((size_t)3 * NB * N_ * 2);  // 11.5 MB
  unsigned short* rank16 = (unsigned short*)alloc((size_t)3 * E_ * 2);
  int2*  csr_pay = (int2*)alloc((size_t)3 * E_ * 8);
  (void)ws_size; (void)in_sizes; (void)n_in; (void)out_size;

  const int row_blocks = (N_ + 127) / 128;  // 235
  const int edge_blocks = (E_ + 255) / 256; // 1875
  const int wave_blocks = (N_ + 3) / 4;     // 7500 (enhance)
  const int agg_blocks = (N_ + 7) / 8;      // 3750 (aggregate, 8 nodes/block)

  const int* d_dst0 = (const int*)d_in[1 + 0 * 9 + 1];
  const int* d_dst1 = (const int*)d_in[1 + 1 * 9 + 1];
  const int* d_dst2 = (const int*)d_in[1 + 2 * 9 + 1];
  const int* d_src0 = (const int*)d_in[1 + 0 * 9 + 0];
  const int* d_src1 = (const int*)d_in[1 + 1 * 9 + 0];
  const int* d_src2 = (const int*)d_in[1 + 2 * 9 + 0];
  const float* d_ew0 = (const float*)d_in[1 + 0 * 9 + 2];
  const float* d_ew1 = (const float*)d_in[1 + 1 * 9 + 2];
  const float* d_ew2 = (const float*)d_in[1 + 2 * 9 + 2];

  // one-time conversions (independent of CSR build)
  convert_h_kernel<<<(N_ * 256 / 8 + 255) / 256, 256, 0, stream>>>(h, hf, N_ * 256 / 8);
  transpose_w_kernel<<<dim3(256, 4), 256, 0, stream>>>(
      (const float*)d_in[1 + 0 * 9 + 5], (const float*)d_in[1 + 1 * 9 + 5],
      (const float*)d_in[1 + 2 * 9 + 5], Wp, WT);
  w12_kernel<<<(256 * 40 + 255) / 256, 256, 0, stream>>>(Wp, W12T);
  f16* WpT = WT + (size_t)3 * 65536;

  // atomic-free CSR build (batched over etypes)
  hist_kernel<<<dim3(NB, 3), 512, 0, stream>>>(d_dst0, d_dst1, d_dst2, ghist, rank16);
  blockpfx_kernel<<<dim3((N_ + 255) / 256, 3), 256, 0, stream>>>(ghist, counts);
  scan_kernel<<<3, 1024, 0, stream>>>(counts, off, N_, E_);
  place_kernel<<<dim3(edge_blocks, 3), 256, 0, stream>>>(
      d_dst0, d_dst1, d_dst2, d_src0, d_src1, d_src2, d_ew0, d_ew1, d_ew2,
      off, ghist, rank16, csr_pay);

  for (int et = 0; et < 3; ++et) {
    const int base = 1 + et * 9;
    const int* nbr_idx = (const int*)d_in[base + 3];
    const float* nbr_w = (const float*)d_in[base + 4];
    const float* al = (const float*)d_in[base + 6];
    const float* ar = (const float*)d_in[base + 7];
    const float* b = (const float*)d_in[base + 8];

    gemm_mfma<0><<<row_blocks, 512, 0, stream>>>(
        hf, WT + (size_t)et * 65536, feat, nullptr, N_, al, ar, el, er,
        nullptr, nullptr, nullptr, nullptr, 256, 0);

    aggregate_kernel<<<agg_blocks, 512, 0, stream>>>(
        off + (size_t)et * (N_ + 1), csr_pay + (size_t)et * E_,
        el, er, (const __half*)feat, b, Wt, Wb, (__half*)gat, gt, gb, N_);

    enhance_pool_kernel<<<wave_blocks, 256, 0, stream>>>(
        nbr_idx, nbr_w, gt, gb, bt, bb, tvec, bvec, N_);

    gemm_mfma<1><<<row_blocks, 512, 0, stream>>>(
        gat, WpT, nullptr, out, N_, nullptr, nullptr, nullptr, nullptr,
        tvec, bvec, W12T, bp, 768, et * 256);
  }
}